// Round 20
// baseline (396.578 us; speedup 1.0000x reference)
//
#include <hip/hip_runtime.h>
#include <math.h>

#define H_ 192
#define W_ 192
#define HW_ (H_*W_)      // 36864
#define B_ 2
#define C_ 64
#define NPIX_ (B_*HW_)   // 73728
#define EPSV 1e-5f

typedef short s8v  __attribute__((ext_vector_type(8)));
typedef float f4v  __attribute__((ext_vector_type(4)));

__device__ __forceinline__ unsigned short f2bf(float f) {
    union { float f; unsigned u; } x; x.f = f;
    unsigned r = x.u + 0x7fffu + ((x.u >> 16) & 1u);   // RNE
    return (unsigned short)(r >> 16);
}
__device__ __forceinline__ float bf2f(unsigned short h) {
    union { unsigned u; float f; } x; x.u = ((unsigned)h) << 16; return x.f;
}

// ---------------------------------------------------------------------------
// Fold: w1t[c][o] = w1[o][c];
//   wkTs[k][g][oc][8] = bf16( sum_o w2[oc,o]*dw[o,c,k] ), g=c>>3
//   wOff[k][oc32][c] = bf16( ow[oc][c][k] ), oc>=18 zero
//   beff[p] = sum_o w2[p,o]*db[o] + b2[p]
// ---------------------------------------------------------------------------
__global__ void k_fold(const float* __restrict__ w1, const float* __restrict__ w2,
                       const float* __restrict__ dw, const float* __restrict__ db,
                       const float* __restrict__ b2, const float* __restrict__ ow,
                       float* __restrict__ w1t, unsigned short* __restrict__ wkTs,
                       unsigned short* __restrict__ wOff, float* __restrict__ beff)
{
    int tid = blockIdx.x * 256 + threadIdx.x;   // 0..36863
    if (tid < 9 * 64 * 64) {
        int k = tid >> 12;
        int r = tid & 4095;
        int c = r >> 6;
        int p = r & 63;
        float acc = 0.f;
        #pragma unroll 8
        for (int o = 0; o < 64; ++o)
            acc = fmaf(w2[p * 64 + o], dw[(o * 64 + c) * 9 + k], acc);
        wkTs[(k << 12) + ((c >> 3) << 9) + (p << 3) + (c & 7)] = f2bf(acc);
    }
    if (tid < 9 * 32 * 64) {       // offconv weights, padded to 32 oc
        int k = tid >> 11;
        int r = tid & 2047;
        int oc = r >> 6;
        int c = r & 63;
        float v = (oc < 18) ? ow[((oc * 64) + c) * 9 + k] : 0.f;
        wOff[tid] = f2bf(v);
    }
    if (tid < 4096) {
        int c = tid >> 6, o = tid & 63;
        w1t[c * 64 + o] = w1[o * 64 + c];
    }
    if (tid < 64) {
        float acc = b2[tid];
        #pragma unroll 8
        for (int o = 0; o < 64; ++o) acc = fmaf(w2[tid * 64 + o], db[o], acc);
        beff[tid] = acc;
    }
}

// ---------------------------------------------------------------------------
// conv1x1 #1 (fp32 VALU) + BN1-stats partials per block (no atomics).
// ---------------------------------------------------------------------------
__global__ __launch_bounds__(256) void k_conv1x1(const float* __restrict__ x,
        const float* __restrict__ w1t, const float* __restrict__ b1,
        float* __restrict__ y, float* __restrict__ part)
{
    __shared__ __align__(16) float xs[64][64];   // [c][p]
    __shared__ __align__(16) float wsh[64][64];  // [c][o]
    int t = threadIdx.x;
    int wg = blockIdx.x;
    int base = wg * 64;
    int b = base / HW_;
    int hw0 = base % HW_;

    #pragma unroll
    for (int i = 0; i < 16; ++i) {
        int e = t + i * 256;
        ((float*)wsh)[e] = w1t[e];
    }
    int p = t & 63, cg = t >> 6;
    #pragma unroll
    for (int i = 0; i < 16; ++i) {
        int c = cg * 16 + i;
        xs[c][p] = x[(b * 64 + c) * HW_ + hw0 + p];
    }
    __syncthreads();

    int l = t & 63, wv = t >> 6;
    int pg = l & 15;
    int og = wv * 4 + (l >> 4);
    float acc[4][4];
    #pragma unroll
    for (int i = 0; i < 4; ++i)
        #pragma unroll
        for (int j = 0; j < 4; ++j) acc[i][j] = 0.f;

    #pragma unroll 8
    for (int c = 0; c < 64; ++c) {
        float va[4], wa[4];
        *(float4*)va = *(const float4*)&xs[c][pg * 4];
        *(float4*)wa = *(const float4*)&wsh[c][og * 4];
        #pragma unroll
        for (int i = 0; i < 4; ++i)
            #pragma unroll
            for (int j = 0; j < 4; ++j)
                acc[i][j] = fmaf(va[i], wa[j], acc[i][j]);
    }

    #pragma unroll
    for (int j = 0; j < 4; ++j) {
        int oc = og * 4 + j;
        float bias = b1[oc];
        float v0 = acc[0][j] + bias, v1 = acc[1][j] + bias;
        float v2 = acc[2][j] + bias, v3 = acc[3][j] + bias;
        *(float4*)&y[(b * 64 + oc) * HW_ + hw0 + pg * 4] =
            make_float4(v0, v1, v2, v3);
        float s = v0 + v1 + v2 + v3;
        float qq = v0 * v0 + v1 * v1 + v2 * v2 + v3 * v3;
        // reduce over the 16 pg lanes (low 4 bits of lane id)
        #pragma unroll
        for (int msk = 8; msk > 0; msk >>= 1) {
            s  += __shfl_xor(s, msk);
            qq += __shfl_xor(qq, msk);
        }
        if (pg == 0) {
            part[(size_t)wg * 128 + oc]      = s;
            part[(size_t)wg * 128 + 64 + oc] = qq;
        }
    }
}

// ---------------------------------------------------------------------------
// statsF: reduce part[nblk][128] -> scale/shift. One block, 256 threads.
// ---------------------------------------------------------------------------
__global__ void k_statsF(const float* __restrict__ part, int nblk,
                         const float* __restrict__ g, const float* __restrict__ be,
                         float* __restrict__ scsh)
{
    __shared__ float tot[128];
    int t = threadIdx.x;
    int slot = t >> 1, half = t & 1;
    float acc = 0.f;
    for (int i = half; i < nblk; i += 2)
        acc += part[(size_t)i * 128 + slot];
    acc += __shfl_xor(acc, 1);
    if (half == 0) tot[slot] = acc;
    __syncthreads();
    if (t < 64) {
        float m = tot[t] / (float)NPIX_;
        float var = tot[64 + t] / (float)NPIX_ - m * m;
        float sc = g[t] * rsqrtf(var + EPSV);
        scsh[t] = sc;
        scsh[64 + t] = be[t] - m * sc;
    }
}

// ---------------------------------------------------------------------------
// BN apply, in place, float4 (final BN2 apply)
// ---------------------------------------------------------------------------
__global__ void k_bn(float* __restrict__ y, const float* __restrict__ scsh, int relu)
{
    int idx = blockIdx.x * 256 + threadIdx.x;         // float4 index
    int c = ((idx * 4) / HW_) & 63;
    float sc = scsh[c], sh = scsh[64 + c];
    float4 v = ((float4*)y)[idx];
    v.x = fmaf(v.x, sc, sh);
    v.y = fmaf(v.y, sc, sh);
    v.z = fmaf(v.z, sc, sh);
    v.w = fmaf(v.w, sc, sh);
    if (relu) {
        v.x = fmaxf(v.x, 0.f); v.y = fmaxf(v.y, 0.f);
        v.z = fmaxf(v.z, 0.f); v.w = fmaxf(v.w, 0.f);
    }
    ((float4*)y)[idx] = v;
}

// ---------------------------------------------------------------------------
// BN1+ReLU -> bf16 NHWC copy ONLY. Thread = 32 ch of one pixel.
// ---------------------------------------------------------------------------
__global__ __launch_bounds__(256) void k_bntr(const float* __restrict__ A,
        const float* __restrict__ scsh, unsigned short* __restrict__ Abf)
{
    __shared__ float scb[64], shb[64];
    int t = threadIdx.x;
    int wg = blockIdx.x;
    int nid = (wg & 7) * 72 + (wg >> 3);     // XCD-chunked over 576
    int base = nid * 128;                    // global pixel base
    int b = base / HW_;
    int hw0 = base % HW_;

    if (t < 64) { scb[t] = scsh[t]; shb[t] = scsh[64 + t]; }
    __syncthreads();

    int pl = t & 127;          // pixel within block
    int chalf = t >> 7;        // 0 or 1 -> channels 32*chalf..+32
    int hw = hw0 + pl;
    size_t gpx = (size_t)base + pl;

    unsigned pk[16];
    #pragma unroll
    for (int c = 0; c < 32; ++c) {
        int ch = chalf * 32 + c;
        size_t idx = ((size_t)(b * 64 + ch)) * HW_ + hw;
        float a = A[idx];
        float v = fmaxf(fmaf(a, scb[ch], shb[ch]), 0.f);
        unsigned bf = f2bf(v);
        if (c & 1) pk[c >> 1] |= bf << 16; else pk[c >> 1] = bf;
    }
    unsigned short* dst = Abf + (gpx << 6) + chalf * 32;
    #pragma unroll
    for (int j = 0; j < 4; ++j)
        *(int4*)&dst[j * 8] = make_int4((int)pk[4 * j], (int)pk[4 * j + 1],
                                        (int)pk[4 * j + 2], (int)pk[4 * j + 3]);
}

// ---------------------------------------------------------------------------
// offset conv3x3 via bf16 MFMA on Abf (NHWC): implicit GEMM, zero pad.
// ---------------------------------------------------------------------------
__global__ __launch_bounds__(64) void k_offconv(const unsigned short* __restrict__ Abf,
        const unsigned short* __restrict__ wOff, const float* __restrict__ ob,
        float* __restrict__ off)
{
    int t = threadIdx.x;
    int wg = blockIdx.x;
    int nid = (wg & 7) * 576 + (wg >> 3);        // XCD-chunked over 4608
    int base = nid * 16;
    int b = base / HW_;
    int hw0 = base % HW_;
    int h = hw0 / W_;
    int w0 = hw0 % W_;

    int m = t & 15, q = t >> 4;
    int wx = w0 + m;
    const unsigned short* Ap = Abf + (((size_t)b * HW_) << 6);
    int cA = q * 8, cB = 32 + q * 8;

    f4v acc0 = (f4v){0.f, 0.f, 0.f, 0.f};
    f4v acc1 = (f4v){0.f, 0.f, 0.f, 0.f};
    const s8v zr = {0, 0, 0, 0, 0, 0, 0, 0};

    #pragma unroll
    for (int k = 0; k < 9; ++k) {
        int yy = h + k / 3 - 1;
        int xx = wx + k % 3 - 1;
        bool valid = (yy >= 0) && (yy < H_) && (xx >= 0) && (xx < W_);
        int yc = min(max(yy, 0), H_ - 1);
        int xc = min(max(xx, 0), W_ - 1);
        size_t ip = (size_t)(yc * W_ + xc) << 6;
        s8v a0 = *(const s8v*)&Ap[ip + cA];
        s8v a1 = *(const s8v*)&Ap[ip + cB];
        if (!valid) { a0 = zr; a1 = zr; }

        const unsigned short* wb = wOff + ((size_t)k << 11);
        s8v b00 = *(const s8v*)&wb[m * 64 + q * 8];
        s8v b01 = *(const s8v*)&wb[m * 64 + 32 + q * 8];
        s8v b10 = *(const s8v*)&wb[(16 + m) * 64 + q * 8];
        s8v b11 = *(const s8v*)&wb[(16 + m) * 64 + 32 + q * 8];

        acc0 = __builtin_amdgcn_mfma_f32_16x16x32_bf16(a0, b00, acc0, 0, 0, 0);
        acc0 = __builtin_amdgcn_mfma_f32_16x16x32_bf16(a1, b01, acc0, 0, 0, 0);
        acc1 = __builtin_amdgcn_mfma_f32_16x16x32_bf16(a0, b10, acc1, 0, 0, 0);
        acc1 = __builtin_amdgcn_mfma_f32_16x16x32_bf16(a1, b11, acc1, 0, 0, 0);
    }

    float biasLo = ob[m];
    float biasHi = (m < 2) ? ob[16 + m] : 0.f;
    #pragma unroll
    for (int r = 0; r < 4; ++r) {
        int px = q * 4 + r;
        off[((size_t)b * 18 + m) * HW_ + hw0 + px] = acc0[r] + biasLo;
        if (m < 2)
            off[((size_t)b * 18 + 16 + m) * HW_ + hw0 + px] = acc1[r] + biasHi;
    }
}

// ---------------------------------------------------------------------------
// R17: FUSED deform = gather(->LDS) + MFMA + BN2 partials. 64 px per block.
// Phase G: thread (pl=t>>2, cg=t&3) bilinearly samples 16 ch of pixel pl for
// all 9 taps; writes bf16 granules to LDS tile Vl[k][px][g^(px&7)]. All 72
// loads/thread independent (no per-tap barrier) -> full MLP.
// Phase M: after one barrier, R16-style MFMA over the LDS tile, W from L2.
// Epilogue: out stores + per-block BN2 sum/sumsq partials (no atomics).
// Dynamic LDS: 9*4096 ushorts (72KB) + 512 floats (2KB) = 75776 B.
// ---------------------------------------------------------------------------
__global__ __launch_bounds__(256) void k_deform2(const unsigned short* __restrict__ Abf,
        const float* __restrict__ offb, const unsigned short* __restrict__ wkTs,
        const float* __restrict__ beff, float* __restrict__ out,
        float* __restrict__ part)
{
    extern __shared__ unsigned short sm[];
    unsigned short* Vl = sm;                    // 9*4096 ushorts
    float* wps = (float*)(sm + 9 * 4096);       // [4][64]
    float* wqs = wps + 256;                     // [4][64]

    int t = threadIdx.x;
    int wg = blockIdx.x;
    int nid = (wg & 7) * 144 + (wg >> 3);       // XCD-chunked over 1152
    int pix0 = nid * 64;
    int b = pix0 / HW_;
    int hwb = pix0 - b * HW_;                   // within-image base (R9 lesson)

    // ======== phase G: gather into LDS ========
    {
        int pl = t >> 2;                 // pixel 0..63
        int cg = t & 3;                  // 16-ch group
        int hw = hwb + pl;
        int h = hw / W_;
        int wx = hw - h * W_;
        const unsigned short* Ap = Abf + (((size_t)b * HW_) << 6);
        int c0 = cg * 16;
        int g0 = (2 * cg) ^ (pl & 7);
        int g1 = (2 * cg + 1) ^ (pl & 7);

        for (int k = 0; k < 9; ++k) {
            float dy = offb[(b * 18 + 2 * k) * HW_ + hw];
            float dx = offb[(b * 18 + 2 * k + 1) * HW_ + hw];
            float py = (float)(h + k / 3 - 1) + dy;
            float px = (float)(wx + k % 3 - 1) + dx;
            float fly = floorf(py), flx = floorf(px);
            float fy = py - fly, fx = px - flx;
            int y0i = (int)fly, x0i = (int)flx;
            float w00 = (1.f - fy) * (1.f - fx);
            float w01 = (1.f - fy) * fx;
            float w10 = fy * (1.f - fx);
            float w11 = fy * fx;
            bool yv0 = (y0i >= 0) && (y0i < H_);
            bool yv1 = (y0i + 1 >= 0) && (y0i + 1 < H_);
            bool xv0 = (x0i >= 0) && (x0i < W_);
            bool xv1 = (x0i + 1 >= 0) && (x0i + 1 < W_);
            if (!(yv0 && xv0)) w00 = 0.f;
            if (!(yv0 && xv1)) w01 = 0.f;
            if (!(yv1 && xv0)) w10 = 0.f;
            if (!(yv1 && xv1)) w11 = 0.f;
            int yc0 = min(max(y0i, 0), H_ - 1), yc1 = min(max(y0i + 1, 0), H_ - 1);
            int xc0 = min(max(x0i, 0), W_ - 1), xc1 = min(max(x0i + 1, 0), W_ - 1);
            size_t i00 = (size_t)(yc0 * W_ + xc0) << 6;
            size_t i01 = (size_t)(yc0 * W_ + xc1) << 6;
            size_t i10 = (size_t)(yc1 * W_ + xc0) << 6;
            size_t i11 = (size_t)(yc1 * W_ + xc1) << 6;

            s8v v00a = *(const s8v*)&Ap[i00 + c0], v00b = *(const s8v*)&Ap[i00 + c0 + 8];
            s8v v01a = *(const s8v*)&Ap[i01 + c0], v01b = *(const s8v*)&Ap[i01 + c0 + 8];
            s8v v10a = *(const s8v*)&Ap[i10 + c0], v10b = *(const s8v*)&Ap[i10 + c0 + 8];
            s8v v11a = *(const s8v*)&Ap[i11 + c0], v11b = *(const s8v*)&Ap[i11 + c0 + 8];

            unsigned pk[8];
            #pragma unroll
            for (int i = 0; i < 4; ++i) {
                unsigned wa = 0, wb = 0;
                #pragma unroll
                for (int jj = 0; jj < 2; ++jj) {
                    int e = 2 * i + jj;
                    float va = bf2f((unsigned short)v00a[e]) * w00
                             + bf2f((unsigned short)v01a[e]) * w01
                             + bf2f((unsigned short)v10a[e]) * w10
                             + bf2f((unsigned short)v11a[e]) * w11;
                    wa |= ((unsigned)f2bf(va)) << (16 * jj);
                    float vb = bf2f((unsigned short)v00b[e]) * w00
                             + bf2f((unsigned short)v01b[e]) * w01
                             + bf2f((unsigned short)v10b[e]) * w10
                             + bf2f((unsigned short)v11b[e]) * w11;
                    wb |= ((unsigned)f2bf(vb)) << (16 * jj);
                }
                pk[i] = wa; pk[4 + i] = wb;
            }
            unsigned short* dst = Vl + k * 4096 + pl * 64;
            *(int4*)&dst[g0 * 8] = make_int4((int)pk[0], (int)pk[1], (int)pk[2], (int)pk[3]);
            *(int4*)&dst[g1 * 8] = make_int4((int)pk[4], (int)pk[5], (int)pk[6], (int)pk[7]);
        }
    }
    __syncthreads();

    // ======== phase M: MFMA over LDS tile ========
    int wv = t >> 6, lane = t & 63;
    int m = lane & 15, q = lane >> 4;
    int rowA = wv * 16 + m;
    int s0 = ((q       ^ (rowA & 7)) << 3);
    int s1 = (((4 + q) ^ (rowA & 7)) << 3);

    f4v acc[4];
    #pragma unroll
    for (int n = 0; n < 4; ++n) acc[n] = (f4v){0.f, 0.f, 0.f, 0.f};

    #pragma unroll
    for (int k = 0; k < 9; ++k) {
        const unsigned short* bv = Vl + k * 4096 + rowA * 64;
        s8v a0 = *(const s8v*)&bv[s0];
        s8v a1 = *(const s8v*)&bv[s1];
        const unsigned short* wkb = wkTs + ((size_t)k << 12);
        #pragma unroll
        for (int n = 0; n < 4; ++n) {
            int oc = n * 16 + m;
            s8v b0 = *(const s8v*)&wkb[(q << 9) + (oc << 3)];
            s8v b1 = *(const s8v*)&wkb[((4 + q) << 9) + (oc << 3)];
            acc[n] = __builtin_amdgcn_mfma_f32_16x16x32_bf16(a0, b0, acc[n], 0, 0, 0);
            acc[n] = __builtin_amdgcn_mfma_f32_16x16x32_bf16(a1, b1, acc[n], 0, 0, 0);
        }
    }

    // ======== epilogue: stores + BN2 partials ========
    int hw0 = hwb + wv * 16;
    #pragma unroll
    for (int n = 0; n < 4; ++n) {
        int oc = n * 16 + m;
        float bias = beff[oc];
        float v0 = acc[n][0] + bias, v1 = acc[n][1] + bias;
        float v2 = acc[n][2] + bias, v3 = acc[n][3] + bias;
        *(float4*)&out[((size_t)b * 64 + oc) * HW_ + hw0 + q * 4] =
            make_float4(v0, v1, v2, v3);
        float s = v0 + v1 + v2 + v3;
        float qq = v0 * v0 + v1 * v1 + v2 * v2 + v3 * v3;
        s  += __shfl_xor(s, 16);  s  += __shfl_xor(s, 32);
        qq += __shfl_xor(qq, 16); qq += __shfl_xor(qq, 32);
        if (q == 0) {
            wps[wv * 64 + oc] = s;
            wqs[wv * 64 + oc] = qq;
        }
    }
    __syncthreads();
    if (t < 64) {
        float S = wps[t] + wps[64 + t] + wps[128 + t] + wps[192 + t];
        float Q = wqs[t] + wqs[64 + t] + wqs[128 + t] + wqs[192 + t];
        part[(size_t)wg * 128 + t]      = S;
        part[(size_t)wg * 128 + 64 + t] = Q;
    }
}

// ---------------------------------------------------------------------------
extern "C" void kernel_launch(void* const* d_in, const int* in_sizes, int n_in,
                              void* d_out, int out_size, void* d_ws, size_t ws_size,
                              hipStream_t stream)
{
    const float* x   = (const float*)d_in[0];
    const float* w1  = (const float*)d_in[1];
    const float* b1  = (const float*)d_in[2];
    const float* g1  = (const float*)d_in[3];
    const float* be1 = (const float*)d_in[4];
    const float* ow  = (const float*)d_in[5];
    const float* ob  = (const float*)d_in[6];
    const float* dw  = (const float*)d_in[7];
    const float* db  = (const float*)d_in[8];
    const float* w2  = (const float*)d_in[9];
    const float* b2  = (const float*)d_in[10];
    const float* g2  = (const float*)d_in[11];
    const float* be2 = (const float*)d_in[12];
    float* out = (float*)d_out;

    float* ws    = (float*)d_ws;
    float* A     = ws;                           // conv1x1 out (raw fp32)
    float* offb  = A + (size_t)NPIX_ * 64;       // 1,327,104 floats
    float* w1t   = offb + (size_t)B_ * 18 * HW_;
    unsigned short* wkTs = (unsigned short*)(w1t + 4096);   // 36,864 bf16
    unsigned short* wOff = wkTs + 9 * 4096;                  // 18,432 bf16
    float* beff  = (float*)(wOff + 9 * 2048);
    float* scsh1 = beff + 64;                    // 128
    float* scsh2 = scsh1 + 128;                  // 128
    float* part  = scsh2 + 128;                  // 1152*128 floats
    unsigned short* Abf = (unsigned short*)(part + 1152 * 128);  // NPIX_*64 bf16

    hipLaunchKernelGGL(k_fold, dim3(144), dim3(256), 0, stream,
                       w1, w2, dw, db, b2, ow, w1t, wkTs, wOff, beff);
    hipLaunchKernelGGL(k_conv1x1, dim3(NPIX_ / 64), dim3(256), 0, stream,
                       x, w1t, b1, A, part);
    hipLaunchKernelGGL(k_statsF, dim3(1), dim3(256), 0, stream,
                       part, NPIX_ / 64, g1, be1, scsh1);
    hipLaunchKernelGGL(k_bntr, dim3(NPIX_ / 128), dim3(256), 0, stream,
                       A, scsh1, Abf);
    hipLaunchKernelGGL(k_offconv, dim3(NPIX_ / 16), dim3(64), 0, stream,
                       Abf, wOff, ob, offb);
    hipLaunchKernelGGL(k_deform2, dim3(NPIX_ / 64), dim3(256), 75776, stream,
                       Abf, offb, wkTs, beff, out, part);
    hipLaunchKernelGGL(k_statsF, dim3(1), dim3(256), 0, stream,
                       part, NPIX_ / 64, g2, be2, scsh2);
    hipLaunchKernelGGL(k_bn, dim3((NPIX_ * 64 / 4) / 256), dim3(256), 0, stream,
                       out, scsh2, 0);
}

// Round 21
// 120.003 us; speedup vs baseline: 3.3047x; 3.3047x over previous
//
#include <hip/hip_runtime.h>
#include <math.h>

#define H_ 192
#define W_ 192
#define HW_ (H_*W_)      // 36864
#define B_ 2
#define C_ 64
#define NPIX_ (B_*HW_)   // 73728
#define NB_ (NPIX_/64)   // 1152 partial-blocks
#define EPSV 1e-5f

typedef short s8v  __attribute__((ext_vector_type(8)));
typedef float f4v  __attribute__((ext_vector_type(4)));

__device__ __forceinline__ unsigned short f2bf(float f) {
    union { float f; unsigned u; } x; x.f = f;
    unsigned r = x.u + 0x7fffu + ((x.u >> 16) & 1u);   // RNE
    return (unsigned short)(r >> 16);
}
__device__ __forceinline__ float bf2f(unsigned short h) {
    union { unsigned u; float f; } x; x.u = ((unsigned)h) << 16; return x.f;
}

// ---------------------------------------------------------------------------
// Fold: w1t[c][o] = w1[o][c];
//   wkTs[k][g][oc][8] = bf16( sum_o w2[oc,o]*dw[o,c,k] ), g=c>>3
//   wOff[k][oc32][c] = bf16( ow[oc][c][k] ), oc>=18 zero
//   beff[p] = sum_o w2[p,o]*db[o] + b2[p]
// ---------------------------------------------------------------------------
__global__ void k_fold(const float* __restrict__ w1, const float* __restrict__ w2,
                       const float* __restrict__ dw, const float* __restrict__ db,
                       const float* __restrict__ b2, const float* __restrict__ ow,
                       float* __restrict__ w1t, unsigned short* __restrict__ wkTs,
                       unsigned short* __restrict__ wOff, float* __restrict__ beff)
{
    int tid = blockIdx.x * 256 + threadIdx.x;   // 0..36863
    if (tid < 9 * 64 * 64) {
        int k = tid >> 12;
        int r = tid & 4095;
        int c = r >> 6;
        int p = r & 63;
        float acc = 0.f;
        #pragma unroll 8
        for (int o = 0; o < 64; ++o)
            acc = fmaf(w2[p * 64 + o], dw[(o * 64 + c) * 9 + k], acc);
        wkTs[(k << 12) + ((c >> 3) << 9) + (p << 3) + (c & 7)] = f2bf(acc);
    }
    if (tid < 9 * 32 * 64) {       // offconv weights, padded to 32 oc
        int k = tid >> 11;
        int r = tid & 2047;
        int oc = r >> 6;
        int c = r & 63;
        float v = (oc < 18) ? ow[((oc * 64) + c) * 9 + k] : 0.f;
        wOff[tid] = f2bf(v);
    }
    if (tid < 4096) {
        int c = tid >> 6, o = tid & 63;
        w1t[c * 64 + o] = w1[o * 64 + c];
    }
    if (tid < 64) {
        float acc = b2[tid];
        #pragma unroll 8
        for (int o = 0; o < 64; ++o) acc = fmaf(w2[tid * 64 + o], db[o], acc);
        beff[tid] = acc;
    }
}

// ---------------------------------------------------------------------------
// conv1x1 #1 (fp32 VALU) + BN1-stats partials, TRANSPOSED part[slot][wg].
// ---------------------------------------------------------------------------
__global__ __launch_bounds__(256) void k_conv1x1(const float* __restrict__ x,
        const float* __restrict__ w1t, const float* __restrict__ b1,
        float* __restrict__ y, float* __restrict__ part)
{
    __shared__ __align__(16) float xs[64][64];   // [c][p]
    __shared__ __align__(16) float wsh[64][64];  // [c][o]
    int t = threadIdx.x;
    int wg = blockIdx.x;
    int base = wg * 64;
    int b = base / HW_;
    int hw0 = base % HW_;

    #pragma unroll
    for (int i = 0; i < 16; ++i) {
        int e = t + i * 256;
        ((float*)wsh)[e] = w1t[e];
    }
    int p = t & 63, cg = t >> 6;
    #pragma unroll
    for (int i = 0; i < 16; ++i) {
        int c = cg * 16 + i;
        xs[c][p] = x[(b * 64 + c) * HW_ + hw0 + p];
    }
    __syncthreads();

    int l = t & 63, wv = t >> 6;
    int pg = l & 15;
    int og = wv * 4 + (l >> 4);
    float acc[4][4];
    #pragma unroll
    for (int i = 0; i < 4; ++i)
        #pragma unroll
        for (int j = 0; j < 4; ++j) acc[i][j] = 0.f;

    #pragma unroll 8
    for (int c = 0; c < 64; ++c) {
        float va[4], wa[4];
        *(float4*)va = *(const float4*)&xs[c][pg * 4];
        *(float4*)wa = *(const float4*)&wsh[c][og * 4];
        #pragma unroll
        for (int i = 0; i < 4; ++i)
            #pragma unroll
            for (int j = 0; j < 4; ++j)
                acc[i][j] = fmaf(va[i], wa[j], acc[i][j]);
    }

    #pragma unroll
    for (int j = 0; j < 4; ++j) {
        int oc = og * 4 + j;
        float bias = b1[oc];
        float v0 = acc[0][j] + bias, v1 = acc[1][j] + bias;
        float v2 = acc[2][j] + bias, v3 = acc[3][j] + bias;
        *(float4*)&y[(b * 64 + oc) * HW_ + hw0 + pg * 4] =
            make_float4(v0, v1, v2, v3);
        float s = v0 + v1 + v2 + v3;
        float qq = v0 * v0 + v1 * v1 + v2 * v2 + v3 * v3;
        #pragma unroll
        for (int msk = 8; msk > 0; msk >>= 1) {
            s  += __shfl_xor(s, msk);
            qq += __shfl_xor(qq, msk);
        }
        if (pg == 0) {
            part[(size_t)oc * NB_ + wg]        = s;
            part[(size_t)(64 + oc) * NB_ + wg] = qq;
        }
    }
}

// ---------------------------------------------------------------------------
// statsC: one block per channel; coalesced-reduce part[c][*], part[64+c][*]
// -> scale/shift directly. 64 blocks x 256 thr; data L2-hot (590KB total).
// ---------------------------------------------------------------------------
__global__ __launch_bounds__(256) void k_statsC(const float* __restrict__ part,
        const float* __restrict__ g, const float* __restrict__ be,
        float* __restrict__ scsh)
{
    int c = blockIdx.x;
    int t = threadIdx.x;
    const float* ps = part + (size_t)c * NB_;
    const float* pq = part + (size_t)(64 + c) * NB_;
    float s = 0.f, q = 0.f;
    for (int i = t; i < NB_; i += 256) {
        s += ps[i];
        q += pq[i];
    }
    int lane = t & 63, wv = t >> 6;
    #pragma unroll
    for (int off = 32; off > 0; off >>= 1) {
        s += __shfl_down(s, off);
        q += __shfl_down(q, off);
    }
    __shared__ float red[8];
    if (lane == 0) { red[wv] = s; red[4 + wv] = q; }
    __syncthreads();
    if (t == 0) {
        float S = red[0] + red[1] + red[2] + red[3];
        float Q = red[4] + red[5] + red[6] + red[7];
        float m = S / (float)NPIX_;
        float var = Q / (float)NPIX_ - m * m;
        float sc = g[c] * rsqrtf(var + EPSV);
        scsh[c] = sc;
        scsh[64 + c] = be[c] - m * sc;
    }
}

// ---------------------------------------------------------------------------
// BN apply, in place, float4 (final BN2 apply)
// ---------------------------------------------------------------------------
__global__ void k_bn(float* __restrict__ y, const float* __restrict__ scsh, int relu)
{
    int idx = blockIdx.x * 256 + threadIdx.x;         // float4 index
    int c = ((idx * 4) / HW_) & 63;
    float sc = scsh[c], sh = scsh[64 + c];
    float4 v = ((float4*)y)[idx];
    v.x = fmaf(v.x, sc, sh);
    v.y = fmaf(v.y, sc, sh);
    v.z = fmaf(v.z, sc, sh);
    v.w = fmaf(v.w, sc, sh);
    if (relu) {
        v.x = fmaxf(v.x, 0.f); v.y = fmaxf(v.y, 0.f);
        v.z = fmaxf(v.z, 0.f); v.w = fmaxf(v.w, 0.f);
    }
    ((float4*)y)[idx] = v;
}

// ---------------------------------------------------------------------------
// BN1+ReLU -> bf16 NHWC copy ONLY. Thread = 32 ch of one pixel.
// ---------------------------------------------------------------------------
__global__ __launch_bounds__(256) void k_bntr(const float* __restrict__ A,
        const float* __restrict__ scsh, unsigned short* __restrict__ Abf)
{
    __shared__ float scb[64], shb[64];
    int t = threadIdx.x;
    int wg = blockIdx.x;
    int nid = (wg & 7) * 72 + (wg >> 3);     // XCD-chunked over 576
    int base = nid * 128;                    // global pixel base
    int b = base / HW_;
    int hw0 = base % HW_;

    if (t < 64) { scb[t] = scsh[t]; shb[t] = scsh[64 + t]; }
    __syncthreads();

    int pl = t & 127;          // pixel within block
    int chalf = t >> 7;        // 0 or 1 -> channels 32*chalf..+32
    int hw = hw0 + pl;
    size_t gpx = (size_t)base + pl;

    unsigned pk[16];
    #pragma unroll
    for (int c = 0; c < 32; ++c) {
        int ch = chalf * 32 + c;
        size_t idx = ((size_t)(b * 64 + ch)) * HW_ + hw;
        float a = A[idx];
        float v = fmaxf(fmaf(a, scb[ch], shb[ch]), 0.f);
        unsigned bf = f2bf(v);
        if (c & 1) pk[c >> 1] |= bf << 16; else pk[c >> 1] = bf;
    }
    unsigned short* dst = Abf + (gpx << 6) + chalf * 32;
    #pragma unroll
    for (int j = 0; j < 4; ++j)
        *(int4*)&dst[j * 8] = make_int4((int)pk[4 * j], (int)pk[4 * j + 1],
                                        (int)pk[4 * j + 2], (int)pk[4 * j + 3]);
}

// ---------------------------------------------------------------------------
// offset conv3x3 via bf16 MFMA on Abf (NHWC): implicit GEMM, zero pad.
// ---------------------------------------------------------------------------
__global__ __launch_bounds__(64) void k_offconv(const unsigned short* __restrict__ Abf,
        const unsigned short* __restrict__ wOff, const float* __restrict__ ob,
        float* __restrict__ off)
{
    int t = threadIdx.x;
    int wg = blockIdx.x;
    int nid = (wg & 7) * 576 + (wg >> 3);        // XCD-chunked over 4608
    int base = nid * 16;
    int b = base / HW_;
    int hw0 = base % HW_;
    int h = hw0 / W_;
    int w0 = hw0 % W_;

    int m = t & 15, q = t >> 4;
    int wx = w0 + m;
    const unsigned short* Ap = Abf + (((size_t)b * HW_) << 6);
    int cA = q * 8, cB = 32 + q * 8;

    f4v acc0 = (f4v){0.f, 0.f, 0.f, 0.f};
    f4v acc1 = (f4v){0.f, 0.f, 0.f, 0.f};
    const s8v zr = {0, 0, 0, 0, 0, 0, 0, 0};

    #pragma unroll
    for (int k = 0; k < 9; ++k) {
        int yy = h + k / 3 - 1;
        int xx = wx + k % 3 - 1;
        bool valid = (yy >= 0) && (yy < H_) && (xx >= 0) && (xx < W_);
        int yc = min(max(yy, 0), H_ - 1);
        int xc = min(max(xx, 0), W_ - 1);
        size_t ip = (size_t)(yc * W_ + xc) << 6;
        s8v a0 = *(const s8v*)&Ap[ip + cA];
        s8v a1 = *(const s8v*)&Ap[ip + cB];
        if (!valid) { a0 = zr; a1 = zr; }

        const unsigned short* wb = wOff + ((size_t)k << 11);
        s8v b00 = *(const s8v*)&wb[m * 64 + q * 8];
        s8v b01 = *(const s8v*)&wb[m * 64 + 32 + q * 8];
        s8v b10 = *(const s8v*)&wb[(16 + m) * 64 + q * 8];
        s8v b11 = *(const s8v*)&wb[(16 + m) * 64 + 32 + q * 8];

        acc0 = __builtin_amdgcn_mfma_f32_16x16x32_bf16(a0, b00, acc0, 0, 0, 0);
        acc0 = __builtin_amdgcn_mfma_f32_16x16x32_bf16(a1, b01, acc0, 0, 0, 0);
        acc1 = __builtin_amdgcn_mfma_f32_16x16x32_bf16(a0, b10, acc1, 0, 0, 0);
        acc1 = __builtin_amdgcn_mfma_f32_16x16x32_bf16(a1, b11, acc1, 0, 0, 0);
    }

    float biasLo = ob[m];
    float biasHi = (m < 2) ? ob[16 + m] : 0.f;
    #pragma unroll
    for (int r = 0; r < 4; ++r) {
        int px = q * 4 + r;
        off[((size_t)b * 18 + m) * HW_ + hw0 + px] = acc0[r] + biasLo;
        if (m < 2)
            off[((size_t)b * 18 + 16 + m) * HW_ + hw0 + px] = acc1[r] + biasHi;
    }
}

// ---------------------------------------------------------------------------
// FUSED deform = gather(->LDS) + MFMA + BN2 partials (transposed layout).
// ---------------------------------------------------------------------------
__global__ __launch_bounds__(256) void k_deform2(const unsigned short* __restrict__ Abf,
        const float* __restrict__ offb, const unsigned short* __restrict__ wkTs,
        const float* __restrict__ beff, float* __restrict__ out,
        float* __restrict__ part)
{
    extern __shared__ unsigned short sm[];
    unsigned short* Vl = sm;                    // 9*4096 ushorts
    float* wps = (float*)(sm + 9 * 4096);       // [4][64]
    float* wqs = wps + 256;                     // [4][64]

    int t = threadIdx.x;
    int wg = blockIdx.x;
    int nid = (wg & 7) * 144 + (wg >> 3);       // XCD-chunked over 1152
    int pix0 = nid * 64;
    int b = pix0 / HW_;
    int hwb = pix0 - b * HW_;                   // within-image base

    // ======== phase G: gather into LDS ========
    {
        int pl = t >> 2;                 // pixel 0..63
        int cg = t & 3;                  // 16-ch group
        int hw = hwb + pl;
        int h = hw / W_;
        int wx = hw - h * W_;
        const unsigned short* Ap = Abf + (((size_t)b * HW_) << 6);
        int c0 = cg * 16;
        int g0 = (2 * cg) ^ (pl & 7);
        int g1 = (2 * cg + 1) ^ (pl & 7);

        for (int k = 0; k < 9; ++k) {
            float dy = offb[(b * 18 + 2 * k) * HW_ + hw];
            float dx = offb[(b * 18 + 2 * k + 1) * HW_ + hw];
            float py = (float)(h + k / 3 - 1) + dy;
            float px = (float)(wx + k % 3 - 1) + dx;
            float fly = floorf(py), flx = floorf(px);
            float fy = py - fly, fx = px - flx;
            int y0i = (int)fly, x0i = (int)flx;
            float w00 = (1.f - fy) * (1.f - fx);
            float w01 = (1.f - fy) * fx;
            float w10 = fy * (1.f - fx);
            float w11 = fy * fx;
            bool yv0 = (y0i >= 0) && (y0i < H_);
            bool yv1 = (y0i + 1 >= 0) && (y0i + 1 < H_);
            bool xv0 = (x0i >= 0) && (x0i < W_);
            bool xv1 = (x0i + 1 >= 0) && (x0i + 1 < W_);
            if (!(yv0 && xv0)) w00 = 0.f;
            if (!(yv0 && xv1)) w01 = 0.f;
            if (!(yv1 && xv0)) w10 = 0.f;
            if (!(yv1 && xv1)) w11 = 0.f;
            int yc0 = min(max(y0i, 0), H_ - 1), yc1 = min(max(y0i + 1, 0), H_ - 1);
            int xc0 = min(max(x0i, 0), W_ - 1), xc1 = min(max(x0i + 1, 0), W_ - 1);
            size_t i00 = (size_t)(yc0 * W_ + xc0) << 6;
            size_t i01 = (size_t)(yc0 * W_ + xc1) << 6;
            size_t i10 = (size_t)(yc1 * W_ + xc0) << 6;
            size_t i11 = (size_t)(yc1 * W_ + xc1) << 6;

            s8v v00a = *(const s8v*)&Ap[i00 + c0], v00b = *(const s8v*)&Ap[i00 + c0 + 8];
            s8v v01a = *(const s8v*)&Ap[i01 + c0], v01b = *(const s8v*)&Ap[i01 + c0 + 8];
            s8v v10a = *(const s8v*)&Ap[i10 + c0], v10b = *(const s8v*)&Ap[i10 + c0 + 8];
            s8v v11a = *(const s8v*)&Ap[i11 + c0], v11b = *(const s8v*)&Ap[i11 + c0 + 8];

            unsigned pk[8];
            #pragma unroll
            for (int i = 0; i < 4; ++i) {
                unsigned wa = 0, wb = 0;
                #pragma unroll
                for (int jj = 0; jj < 2; ++jj) {
                    int e = 2 * i + jj;
                    float va = bf2f((unsigned short)v00a[e]) * w00
                             + bf2f((unsigned short)v01a[e]) * w01
                             + bf2f((unsigned short)v10a[e]) * w10
                             + bf2f((unsigned short)v11a[e]) * w11;
                    wa |= ((unsigned)f2bf(va)) << (16 * jj);
                    float vb = bf2f((unsigned short)v00b[e]) * w00
                             + bf2f((unsigned short)v01b[e]) * w01
                             + bf2f((unsigned short)v10b[e]) * w10
                             + bf2f((unsigned short)v11b[e]) * w11;
                    wb |= ((unsigned)f2bf(vb)) << (16 * jj);
                }
                pk[i] = wa; pk[4 + i] = wb;
            }
            unsigned short* dst = Vl + k * 4096 + pl * 64;
            *(int4*)&dst[g0 * 8] = make_int4((int)pk[0], (int)pk[1], (int)pk[2], (int)pk[3]);
            *(int4*)&dst[g1 * 8] = make_int4((int)pk[4], (int)pk[5], (int)pk[6], (int)pk[7]);
        }
    }
    __syncthreads();

    // ======== phase M: MFMA over LDS tile ========
    int wv = t >> 6, lane = t & 63;
    int m = lane & 15, q = lane >> 4;
    int rowA = wv * 16 + m;
    int s0 = ((q       ^ (rowA & 7)) << 3);
    int s1 = (((4 + q) ^ (rowA & 7)) << 3);

    f4v acc[4];
    #pragma unroll
    for (int n = 0; n < 4; ++n) acc[n] = (f4v){0.f, 0.f, 0.f, 0.f};

    #pragma unroll
    for (int k = 0; k < 9; ++k) {
        const unsigned short* bv = Vl + k * 4096 + rowA * 64;
        s8v a0 = *(const s8v*)&bv[s0];
        s8v a1 = *(const s8v*)&bv[s1];
        const unsigned short* wkb = wkTs + ((size_t)k << 12);
        #pragma unroll
        for (int n = 0; n < 4; ++n) {
            int oc = n * 16 + m;
            s8v b0 = *(const s8v*)&wkb[(q << 9) + (oc << 3)];
            s8v b1 = *(const s8v*)&wkb[((4 + q) << 9) + (oc << 3)];
            acc[n] = __builtin_amdgcn_mfma_f32_16x16x32_bf16(a0, b0, acc[n], 0, 0, 0);
            acc[n] = __builtin_amdgcn_mfma_f32_16x16x32_bf16(a1, b1, acc[n], 0, 0, 0);
        }
    }

    // ======== epilogue: stores + BN2 partials (transposed) ========
    int hw0 = hwb + wv * 16;
    #pragma unroll
    for (int n = 0; n < 4; ++n) {
        int oc = n * 16 + m;
        float bias = beff[oc];
        float v0 = acc[n][0] + bias, v1 = acc[n][1] + bias;
        float v2 = acc[n][2] + bias, v3 = acc[n][3] + bias;
        *(float4*)&out[((size_t)b * 64 + oc) * HW_ + hw0 + q * 4] =
            make_float4(v0, v1, v2, v3);
        float s = v0 + v1 + v2 + v3;
        float qq = v0 * v0 + v1 * v1 + v2 * v2 + v3 * v3;
        s  += __shfl_xor(s, 16);  s  += __shfl_xor(s, 32);
        qq += __shfl_xor(qq, 16); qq += __shfl_xor(qq, 32);
        if (q == 0) {
            wps[wv * 64 + oc] = s;
            wqs[wv * 64 + oc] = qq;
        }
    }
    __syncthreads();
    if (t < 64) {
        float S = wps[t] + wps[64 + t] + wps[128 + t] + wps[192 + t];
        float Q = wqs[t] + wqs[64 + t] + wqs[128 + t] + wqs[192 + t];
        part[(size_t)t * NB_ + wg]        = S;
        part[(size_t)(64 + t) * NB_ + wg] = Q;
    }
}

// ---------------------------------------------------------------------------
extern "C" void kernel_launch(void* const* d_in, const int* in_sizes, int n_in,
                              void* d_out, int out_size, void* d_ws, size_t ws_size,
                              hipStream_t stream)
{
    const float* x   = (const float*)d_in[0];
    const float* w1  = (const float*)d_in[1];
    const float* b1  = (const float*)d_in[2];
    const float* g1  = (const float*)d_in[3];
    const float* be1 = (const float*)d_in[4];
    const float* ow  = (const float*)d_in[5];
    const float* ob  = (const float*)d_in[6];
    const float* dw  = (const float*)d_in[7];
    const float* db  = (const float*)d_in[8];
    const float* w2  = (const float*)d_in[9];
    const float* b2  = (const float*)d_in[10];
    const float* g2  = (const float*)d_in[11];
    const float* be2 = (const float*)d_in[12];
    float* out = (float*)d_out;

    float* ws    = (float*)d_ws;
    float* A     = ws;                           // conv1x1 out (raw fp32)
    float* offb  = A + (size_t)NPIX_ * 64;       // 1,327,104 floats
    float* w1t   = offb + (size_t)B_ * 18 * HW_;
    unsigned short* wkTs = (unsigned short*)(w1t + 4096);   // 36,864 bf16
    unsigned short* wOff = wkTs + 9 * 4096;                  // 18,432 bf16
    float* beff  = (float*)(wOff + 9 * 2048);
    float* scsh1 = beff + 64;                    // 128
    float* scsh2 = scsh1 + 128;                  // 128
    float* part  = scsh2 + 128;                  // 128*NB_ floats
    unsigned short* Abf = (unsigned short*)(part + 128 * NB_);  // NPIX_*64 bf16

    hipLaunchKernelGGL(k_fold, dim3(144), dim3(256), 0, stream,
                       w1, w2, dw, db, b2, ow, w1t, wkTs, wOff, beff);
    hipLaunchKernelGGL(k_conv1x1, dim3(NPIX_ / 64), dim3(256), 0, stream,
                       x, w1t, b1, A, part);
    hipLaunchKernelGGL(k_statsC, dim3(64), dim3(256), 0, stream,
                       part, g1, be1, scsh1);
    hipLaunchKernelGGL(k_bntr, dim3(NPIX_ / 128), dim3(256), 0, stream,
                       A, scsh1, Abf);
    hipLaunchKernelGGL(k_offconv, dim3(NPIX_ / 16), dim3(64), 0, stream,
                       Abf, wOff, ob, offb);
    hipLaunchKernelGGL(k_deform2, dim3(NPIX_ / 64), dim3(256), 75776, stream,
                       Abf, offb, wkTs, beff, out, part);
    hipLaunchKernelGGL(k_statsC, dim3(64), dim3(256), 0, stream,
                       part, g2, be2, scsh2);
    hipLaunchKernelGGL(k_bn, dim3((NPIX_ * 64 / 4) / 256), dim3(256), 0, stream,
                       out, scsh2, 0);
}